// Round 3
// baseline (744.200 us; speedup 1.0000x reference)
//
#include <hip/hip_runtime.h>
#include <hip/hip_bf16.h>
#include <cstddef>

#define D_IN 128
#define D_E 64
#define D_MID 64

typedef __attribute__((ext_vector_type(8))) short bf16x8;
typedef __attribute__((ext_vector_type(4))) float f32x4;
typedef __attribute__((ext_vector_type(4))) int i32x4;

// ---- fp32 -> (hi, lo) bf16 split: hi = truncate-to-bf16, lo = rne(f - hi) ----
__device__ __forceinline__ short bf16_rne(float f) {
    __hip_bfloat16 h = __float2bfloat16(f);
    union { __hip_bfloat16 h; short s; } u; u.h = h;
    return u.s;
}

__device__ __forceinline__ void split2(float f, short& hi, short& lo) {
    unsigned u  = __float_as_uint(f);
    unsigned uh = u & 0xffff0000u;          // truncated bf16 (exact in fp32)
    hi = (short)(uh >> 16);
    lo = bf16_rne(f - __uint_as_float(uh)); // residual, rounded to bf16
}

// =====================================================================
// Kernel 1: P[n][0:64]  = emb[n] @ W1_src + b1   (src projection, bias folded)
//           P[n][64:128]= emb[n] @ W1_dst        (dst projection)
// 128 threads (thread j = output column j), 16 nodes per block.
// emb reads are wave-uniform -> scalar loads; W reads coalesced, L2-resident.
// =====================================================================
__global__ __launch_bounds__(128) void proj_kernel(
    const float* __restrict__ emb, const float* __restrict__ W1,
    const float* __restrict__ b1, float* __restrict__ P)
{
    const int j  = threadIdx.x;          // 0..127
    const int nb = blockIdx.x * 16;      // node base
    // column j<64 -> W1_src (rows 0..127); j>=64 -> W1_dst (rows 128..255)
    const float* Wbase = (j < 64) ? (W1 + j) : (W1 + 128 * 64 + (j - 64));

    float acc[16];
    #pragma unroll
    for (int i = 0; i < 16; ++i) acc[i] = 0.f;

    for (int kc = 0; kc < 8; ++kc) {     // 8 chunks of 16 k
        float w[16];
        #pragma unroll
        for (int kk = 0; kk < 16; ++kk) w[kk] = Wbase[(kc * 16 + kk) * 64];
        #pragma unroll
        for (int i = 0; i < 16; ++i) {
            const float* e = emb + (size_t)(nb + i) * 128 + kc * 16; // uniform
            #pragma unroll
            for (int kk = 0; kk < 16; ++kk)
                acc[i] = fmaf(e[kk], w[kk], acc[i]);
        }
    }
    const float bias = (j < 64) ? b1[j] : 0.f;
    #pragma unroll
    for (int i = 0; i < 16; ++i)
        P[(size_t)(nb + i) * 128 + j] = acc[i] + bias;
}

// =====================================================================
// Kernel 2: per edge e: out[e] = W2 . relu(P[src][0:64] + P[dst][64:128]
//                                          + ef[e] @ W1_e) + b2
// 4 waves/block, each wave does 8 MFMA tiles of 16 edges (512 edges/block).
// Edge matmul via bf16 split-precision MFMA (hi*hi + hi*lo + lo*hi).
// ef is streamed with NON-TEMPORAL loads so the 410 MB stream does not
// evict P (25.6 MB, reused ~32x/node) from L2/L3 — the P gathers are the
// critical path of this kernel.
// =====================================================================
__global__ __launch_bounds__(256) void edge_kernel(
    const float* __restrict__ ef,  const int* __restrict__ src,
    const int* __restrict__ dst,   const float* __restrict__ P,
    const float* __restrict__ W1,  const float* __restrict__ W2,
    const float* __restrict__ b2p, float* __restrict__ out)
{
    const int lane = threadIdx.x & 63;
    const int lr   = lane & 15;
    const int lg   = lane >> 4;
    const int wid  = threadIdx.x >> 6;
    const int wave = blockIdx.x * 4 + wid;
    const int ebase0 = wave * 128;         // 8 tiles * 16 edges

    // ---- W1_e (rows 256..319 of W1) -> B fragments, hi/lo split, once ----
    const float* We = W1 + 256 * 64;
    bf16x8 bhi[2][4], blo[2][4];
    #pragma unroll
    for (int ks = 0; ks < 2; ++ks)
        #pragma unroll
        for (int nt = 0; nt < 4; ++nt) {
            #pragma unroll
            for (int i = 0; i < 8; ++i) {
                // two K=16 halves: elems 0..3 -> k=lg*4+i, elems 4..7 -> k=16+lg*4+(i-4)
                int kl = (i < 4) ? (lg * 4 + i) : (16 + lg * 4 + (i - 4));
                float f = We[(ks * 32 + kl) * 64 + nt * 16 + lr];
                short h, l; split2(f, h, l);
                bhi[ks][nt][i] = h; blo[ks][nt][i] = l;
            }
        }

    float w2v[4];
    #pragma unroll
    for (int nt = 0; nt < 4; ++nt) w2v[nt] = W2[nt * 16 + lr];
    const float b2 = b2p[0];

    // prefetch tile 0 indices (non-temporal: single-use stream)
    i32x4 s4 = __builtin_nontemporal_load((const i32x4*)(src + ebase0 + lg * 4));
    i32x4 d4 = __builtin_nontemporal_load((const i32x4*)(dst + ebase0 + lg * 4));

    for (int t = 0; t < 8; ++t) {
        const int eb = ebase0 + t * 16;

        // prefetch next tile's indices (overlaps with MFMA below)
        i32x4 s4n, d4n;
        if (t < 7) {
            s4n = __builtin_nontemporal_load((const i32x4*)(src + eb + 16 + lg * 4));
            d4n = __builtin_nontemporal_load((const i32x4*)(dst + eb + 16 + lg * 4));
        }

        f32x4 acc[4];
        #pragma unroll
        for (int nt = 0; nt < 4; ++nt) acc[nt] = (f32x4){0.f, 0.f, 0.f, 0.f};

        #pragma unroll
        for (int ks = 0; ks < 2; ++ks) {
            // A fragment: edge m = eb + lr, k = ks*32 + {lg*4+0..3, 16+lg*4+0..3}
            const float* abase = ef + (size_t)(eb + lr) * 64 + ks * 32 + lg * 4;
            f32x4 a0 = __builtin_nontemporal_load((const f32x4*)(abase));
            f32x4 a1 = __builtin_nontemporal_load((const f32x4*)(abase + 16));
            bf16x8 ahi, alo;
            #pragma unroll
            for (int i = 0; i < 4; ++i) {
                short h, l;
                split2(a0[i], h, l); ahi[i]     = h; alo[i]     = l;
                split2(a1[i], h, l); ahi[i + 4] = h; alo[i + 4] = l;
            }
            #pragma unroll
            for (int nt = 0; nt < 4; ++nt) {
                acc[nt] = __builtin_amdgcn_mfma_f32_16x16x32_bf16(ahi, bhi[ks][nt], acc[nt], 0, 0, 0);
                acc[nt] = __builtin_amdgcn_mfma_f32_16x16x32_bf16(ahi, blo[ks][nt], acc[nt], 0, 0, 0);
                acc[nt] = __builtin_amdgcn_mfma_f32_16x16x32_bf16(alo, bhi[ks][nt], acc[nt], 0, 0, 0);
            }
        }

        // ---- epilogue: gather P, relu, dot W2, 16-lane reduce ----
        #pragma unroll
        for (int r = 0; r < 4; ++r) {
            const float* Ps = P + (size_t)s4[r] * 128 + lr;        // src half
            const float* Pd = P + (size_t)d4[r] * 128 + 64 + lr;   // dst half
            float tot = 0.f;
            #pragma unroll
            for (int nt = 0; nt < 4; ++nt) {
                float h = acc[nt][r] + Ps[nt * 16] + Pd[nt * 16];
                h = fmaxf(h, 0.f);
                tot = fmaf(h, w2v[nt], tot);
            }
            tot += __shfl_xor(tot, 1);
            tot += __shfl_xor(tot, 2);
            tot += __shfl_xor(tot, 4);
            tot += __shfl_xor(tot, 8);
            if (lr == 0)
                __builtin_nontemporal_store(tot + b2, out + eb + lg * 4 + r);
        }

        s4 = s4n; d4 = d4n;
    }
}

extern "C" void kernel_launch(void* const* d_in, const int* in_sizes, int n_in,
                              void* d_out, int out_size, void* d_ws, size_t ws_size,
                              hipStream_t stream) {
    const float* emb = (const float*)d_in[0];
    const int*   src = (const int*)  d_in[1];
    const int*   dst = (const int*)  d_in[2];
    const float* ef  = (const float*)d_in[3];
    const float* W1  = (const float*)d_in[4];
    const float* b1  = (const float*)d_in[5];
    const float* W2  = (const float*)d_in[6];
    const float* b2  = (const float*)d_in[7];
    float* P   = (float*)d_ws;     // 50000*128*4 = 25.6 MB
    float* out = (float*)d_out;

    // 50000 nodes / 16 per block = 3125 blocks
    hipLaunchKernelGGL(proj_kernel, dim3(3125), dim3(128), 0, stream, emb, W1, b1, P);
    // 1.6M edges / 512 per block = 3125 blocks
    hipLaunchKernelGGL(edge_kernel, dim3(3125), dim3(256), 0, stream,
                       ef, src, dst, P, W1, W2, b2, out);
}

// Round 5
// 727.584 us; speedup vs baseline: 1.0228x; 1.0228x over previous
//
#include <hip/hip_runtime.h>
#include <hip/hip_bf16.h>
#include <cstddef>

#define D_IN 128
#define D_E 64
#define D_MID 64

typedef __attribute__((ext_vector_type(8))) short bf16x8;
typedef __attribute__((ext_vector_type(4))) float f32x4;
typedef __attribute__((ext_vector_type(4))) int i32x4;

__device__ __forceinline__ short bf16_rne(float f) {
    __hip_bfloat16 h = __float2bfloat16(f);
    union { __hip_bfloat16 h; short s; } u; u.h = h;
    return u.s;
}

// =====================================================================
// Kernel 1: P[n][0:64]  = emb[n] @ W1_src + b1   (src projection, bias folded)
//           P[n][64:128]= emb[n] @ W1_dst        (dst projection)
// 128 threads (thread j = output column j), 16 nodes per block.
// =====================================================================
__global__ __launch_bounds__(128) void proj_kernel(
    const float* __restrict__ emb, const float* __restrict__ W1,
    const float* __restrict__ b1, float* __restrict__ P)
{
    const int j  = threadIdx.x;          // 0..127
    const int nb = blockIdx.x * 16;      // node base
    const float* Wbase = (j < 64) ? (W1 + j) : (W1 + 128 * 64 + (j - 64));

    float acc[16];
    #pragma unroll
    for (int i = 0; i < 16; ++i) acc[i] = 0.f;

    for (int kc = 0; kc < 8; ++kc) {     // 8 chunks of 16 k
        float w[16];
        #pragma unroll
        for (int kk = 0; kk < 16; ++kk) w[kk] = Wbase[(kc * 16 + kk) * 64];
        #pragma unroll
        for (int i = 0; i < 16; ++i) {
            const float* e = emb + (size_t)(nb + i) * 128 + kc * 16; // uniform
            #pragma unroll
            for (int kk = 0; kk < 16; ++kk)
                acc[i] = fmaf(e[kk], w[kk], acc[i]);
        }
    }
    const float bias = (j < 64) ? b1[j] : 0.f;
    #pragma unroll
    for (int i = 0; i < 16; ++i)
        P[(size_t)(nb + i) * 128 + j] = acc[i] + bias;
}

// =====================================================================
// Kernel 2: per edge e: out[e] = W2 . relu(P[src][0:64] + P[dst][64:128]
//                                          + ef[e] @ W1_e) + b2
// 4 waves/block, 8 MFMA tiles of 16 edges per wave (512 edges/block).
// A (ef) split hi/lo bf16; B (W1_e) rne bf16 only -> 16 MFMAs/tile.
// Gathers issued at tile top to overlap MFMA; VGPR<=128 for 4 waves/SIMD.
// =====================================================================
__global__ __launch_bounds__(256, 4) void edge_kernel(
    const float* __restrict__ ef,  const int* __restrict__ src,
    const int* __restrict__ dst,   const float* __restrict__ P,
    const float* __restrict__ W1,  const float* __restrict__ W2,
    const float* __restrict__ b2p, float* __restrict__ out)
{
    const int lane = threadIdx.x & 63;
    const int lr   = lane & 15;
    const int lg   = lane >> 4;
    const int wid  = threadIdx.x >> 6;
    const int wave = blockIdx.x * 4 + wid;
    const int ebase0 = wave * 128;         // 8 tiles * 16 edges

    // ---- W1_e (rows 256..319 of W1) -> B fragments, rne bf16, once ----
    const float* We = W1 + 256 * 64;
    bf16x8 bh[2][4];
    #pragma unroll
    for (int ks = 0; ks < 2; ++ks)
        #pragma unroll
        for (int nt = 0; nt < 4; ++nt)
            #pragma unroll
            for (int i = 0; i < 8; ++i) {
                int kl = (i < 4) ? (lg * 4 + i) : (16 + lg * 4 + (i - 4));
                bh[ks][nt][i] = bf16_rne(We[(ks * 32 + kl) * 64 + nt * 16 + lr]);
            }

    float w2v[4];
    #pragma unroll
    for (int nt = 0; nt < 4; ++nt) w2v[nt] = W2[nt * 16 + lr];
    const float b2 = b2p[0];

    // prefetch tile 0 indices (non-temporal single-use stream)
    i32x4 s4 = __builtin_nontemporal_load((const i32x4*)(src + ebase0 + lg * 4));
    i32x4 d4 = __builtin_nontemporal_load((const i32x4*)(dst + ebase0 + lg * 4));

    for (int t = 0; t < 8; ++t) {
        const int eb = ebase0 + t * 16;

        // ---- issue this tile's ef loads (streaming) ----
        f32x4 a0[2], a1[2];
        #pragma unroll
        for (int ks = 0; ks < 2; ++ks) {
            const float* ab = ef + (size_t)(eb + lr) * 64 + ks * 32 + lg * 4;
            a0[ks] = __builtin_nontemporal_load((const f32x4*)(ab));
            a1[ks] = __builtin_nontemporal_load((const f32x4*)(ab + 16));
        }

        // ---- issue this tile's P gathers (cached; overlap with MFMA) ----
        float padd[4][4];
        #pragma unroll
        for (int r = 0; r < 4; ++r) {
            const float* Ps = P + (size_t)s4[r] * 128 + lr;        // src half
            const float* Pd = P + (size_t)d4[r] * 128 + 64 + lr;   // dst half
            #pragma unroll
            for (int nt = 0; nt < 4; ++nt)
                padd[r][nt] = Ps[nt * 16] + Pd[nt * 16];
        }

        // ---- prefetch next tile's indices ----
        i32x4 s4n, d4n;
        if (t < 7) {
            s4n = __builtin_nontemporal_load((const i32x4*)(src + eb + 16 + lg * 4));
            d4n = __builtin_nontemporal_load((const i32x4*)(dst + eb + 16 + lg * 4));
        }

        // ---- split A and MFMA ----
        f32x4 acc[4];
        #pragma unroll
        for (int nt = 0; nt < 4; ++nt) acc[nt] = (f32x4){0.f, 0.f, 0.f, 0.f};

        #pragma unroll
        for (int ks = 0; ks < 2; ++ks) {
            bf16x8 ahi, alo;
            #pragma unroll
            for (int i = 0; i < 4; ++i) {
                float f0 = a0[ks][i], f1 = a1[ks][i];
                unsigned u0 = __float_as_uint(f0), u1 = __float_as_uint(f1);
                ahi[i]     = (short)(u0 >> 16);                    // trunc bf16
                ahi[i + 4] = (short)(u1 >> 16);
                alo[i]     = bf16_rne(f0 - __uint_as_float(u0 & 0xffff0000u));
                alo[i + 4] = bf16_rne(f1 - __uint_as_float(u1 & 0xffff0000u));
            }
            #pragma unroll
            for (int nt = 0; nt < 4; ++nt) {
                acc[nt] = __builtin_amdgcn_mfma_f32_16x16x32_bf16(ahi, bh[ks][nt], acc[nt], 0, 0, 0);
                acc[nt] = __builtin_amdgcn_mfma_f32_16x16x32_bf16(alo, bh[ks][nt], acc[nt], 0, 0, 0);
            }
        }

        // ---- epilogue: relu, dot W2, 16-lane reduce ----
        #pragma unroll
        for (int r = 0; r < 4; ++r) {
            float tot = 0.f;
            #pragma unroll
            for (int nt = 0; nt < 4; ++nt) {
                float h = acc[nt][r] + padd[r][nt];
                h = fmaxf(h, 0.f);
                tot = fmaf(h, w2v[nt], tot);
            }
            tot += __shfl_xor(tot, 1);
            tot += __shfl_xor(tot, 2);
            tot += __shfl_xor(tot, 4);
            tot += __shfl_xor(tot, 8);
            if (lr == 0)
                __builtin_nontemporal_store(tot + b2, out + eb + lg * 4 + r);
        }

        s4 = s4n; d4 = d4n;
    }
}

extern "C" void kernel_launch(void* const* d_in, const int* in_sizes, int n_in,
                              void* d_out, int out_size, void* d_ws, size_t ws_size,
                              hipStream_t stream) {
    const float* emb = (const float*)d_in[0];
    const int*   src = (const int*)  d_in[1];
    const int*   dst = (const int*)  d_in[2];
    const float* ef  = (const float*)d_in[3];
    const float* W1  = (const float*)d_in[4];
    const float* b1  = (const float*)d_in[5];
    const float* W2  = (const float*)d_in[6];
    const float* b2  = (const float*)d_in[7];
    float* P   = (float*)d_ws;     // 50000*128*4 = 25.6 MB
    float* out = (float*)d_out;

    hipLaunchKernelGGL(proj_kernel, dim3(3125), dim3(128), 0, stream, emb, W1, b1, P);
    hipLaunchKernelGGL(edge_kernel, dim3(3125), dim3(256), 0, stream,
                       ef, src, dst, P, W1, W2, b2, out);
}